// Round 17
// baseline (173.197 us; speedup 1.0000x reference)
//
#include <hip/hip_runtime.h>

// GIN forward: transformed-space linearity (y = h@wa; agg@wa = y_self + sum y_nbr)
// fp16 ping-pong activation tables, CSR via bucket binning + packed counting
// sort (pre-transform hidden under bin_fill), FUSED per-layer kernel:
// 4-node/16-lane gather agg (8-deep) + BN/ReLU -> wave-private LDS t-tile ->
// MFMA-f16 MLP (weights pre-fragmented in VGPRs) -> y' store; 1 tile/wave.
// Per-graph fused pool+head. N=100000, E=1200000, DIM=64, G=1000, IN=11.

#define BN_EPS 1e-5f
#define NBUCK 512
#define NBLK  256

typedef __attribute__((ext_vector_type(8))) _Float16 half8v;  // 8 f16 (4 VGPRs)
typedef __attribute__((ext_vector_type(4))) _Float16 half4v;  // 4 f16 (2 VGPRs)
typedef __attribute__((ext_vector_type(4))) float float4v;    // 4 fp32 acc

// ---- setup: [0,256) hist+zero pad rows, [256,261) wfrag, [261,261+GB) gptr -
__global__ __launch_bounds__(256)
void setup_kernel(const int* __restrict__ dst, int* __restrict__ ghist,
                  int E, int chunk,
                  _Float16* __restrict__ padA, _Float16* __restrict__ padB,
                  const int* __restrict__ batch, int* __restrict__ gptr,
                  int N, int G,
                  const float* __restrict__ w0, const float* __restrict__ w1,
                  const float* __restrict__ w2, const float* __restrict__ w3,
                  const float* __restrict__ w4, _Float16* __restrict__ fwout) {
    __shared__ int h[NBUCK];
    const int blk = blockIdx.x, tid = threadIdx.x;

    if (blk < NBLK) {
        if (blk == 0 && tid < 64) {
            padA[tid] = (_Float16)0.f;
            padB[tid] = (_Float16)0.f;
        }
        for (int u = tid; u < NBUCK; u += 256) h[u] = 0;
        __syncthreads();
        const int e0 = blk * chunk, e1 = min(E, e0 + chunk);
        for (int e = e0 + tid; e < e1; e += 256)
            atomicAdd(&h[dst[e] >> 8], 1);
        __syncthreads();
        for (int u = tid; u < NBUCK; u += 256)
            ghist[u * NBLK + blk] = h[u];
    } else if (blk < NBLK + 5) {
        const int m = blk - NBLK;
        const float* w = (m == 0) ? w0 : (m == 1) ? w1 : (m == 2) ? w2 :
                         (m == 3) ? w3 : w4;
        _Float16* o = fwout + (size_t)m * 4096;
        const int lane = tid & 63;
        const int cb   = tid >> 6;
        const int half = lane >> 4, sub = lane & 15;
        #pragma unroll
        for (int it = 0; it < 2; ++it) {
            int c = cb + 4 * it;             // 0..7 = kk*4 + nt
            int kk = c >> 2, nt = c & 3;
            _Float16 f[8];
            #pragma unroll
            for (int j = 0; j < 8; ++j)
                f[j] = (_Float16)w[(kk * 32 + half * 8 + j) * 64 + nt * 16 + sub];
            *(half8v*)&o[((size_t)c * 64 + lane) * 8] = *(half8v*)f;
        }
    } else {
        int i = (blk - NBLK - 5) * 256 + tid;
        if (i < N) {
            int b = batch[i];
            int bprev = (i == 0) ? -1 : batch[i - 1];
            for (int g = bprev + 1; g <= b; ++g) gptr[g] = i;
            if (i == N - 1)
                for (int g = b + 1; g <= G; ++g) gptr[g] = N;
        }
    }
}

// ---------------- hierarchical exclusive scan ------------------------------
__global__ __launch_bounds__(256)
void scan_block_g(int* __restrict__ a, int* __restrict__ bsum, int n) {
    __shared__ int s[256];
    int i = blockIdx.x * 256 + threadIdx.x;
    int v = (i < n) ? a[i] : 0;
    s[threadIdx.x] = v;
    __syncthreads();
    for (int off = 1; off < 256; off <<= 1) {
        int t = (threadIdx.x >= off) ? s[threadIdx.x - off] : 0;
        __syncthreads();
        s[threadIdx.x] += t;
        __syncthreads();
    }
    if (i < n) a[i] = s[threadIdx.x] - v;
    if (threadIdx.x == 255) bsum[blockIdx.x] = s[255];
}

__global__ __launch_bounds__(512)
void scan_top_kernel(int* bsum, int nb) {
    __shared__ int s[512];
    int v = (threadIdx.x < nb) ? bsum[threadIdx.x] : 0;
    s[threadIdx.x] = v;
    __syncthreads();
    for (int off = 1; off < 512; off <<= 1) {
        int t = (threadIdx.x >= off) ? s[threadIdx.x - off] : 0;
        __syncthreads();
        s[threadIdx.x] += t;
        __syncthreads();
    }
    if (threadIdx.x < nb) bsum[threadIdx.x] = s[threadIdx.x] - v;
}

// ---- bin fill + pre-transform (role-split, independent work) --------------
// blocks [0,NBLK): clustered packed pair writes via block-local LDS cursors
// blocks [NBLK, ...): yh = f16(x @ w1a)
// packed pair: (dstLocal << 24) | src   (src < 2^24)
__global__ __launch_bounds__(256)
void fill_pre_kernel(const int* __restrict__ src, const int* __restrict__ dst,
                     const int* __restrict__ ghist, const int* __restrict__ bsum,
                     unsigned* __restrict__ pairs, int E, int chunk,
                     const float* __restrict__ x, const float* __restrict__ wa,
                     _Float16* __restrict__ yh, int n) {
    __shared__ int cur[NBUCK];
    __shared__ float s_wa[11 * 64];
    __shared__ float s_row[4][11];
    const int tid = threadIdx.x, blk = blockIdx.x;

    if (blk < NBLK) {
        // ---- bin fill ----
        for (int u = tid; u < NBUCK; u += 256)
            cur[u] = ghist[u * NBLK + blk] + bsum[u];
        __syncthreads();
        const int e0 = blk * chunk, e1 = min(E, e0 + chunk);
        for (int e = e0 + tid; e < e1; e += 256) {
            int d = dst[e];
            int pos = atomicAdd(&cur[d >> 8], 1);
            pairs[pos] = ((unsigned)(d & 255) << 24) | (unsigned)src[e];
        }
    } else {
        // ---- pre-transform ----
        const int pb = blk - NBLK;
        const int nPre = gridDim.x - NBLK;
        const int lane = tid & 63;
        const int local = tid >> 6;
        for (int i = tid; i < 11 * 64; i += 256) s_wa[i] = wa[i];
        __syncthreads();
        const int groups = (n + 3) >> 2;
        for (int grp = pb; grp < groups; grp += nPre) {
            const int node = grp * 4 + local;
            if (node >= n) continue;
            if (lane < 11) s_row[local][lane] = x[(size_t)node * 11 + lane];
            float acc = 0.f;
            #pragma unroll
            for (int k = 0; k < 11; ++k)
                acc = fmaf(s_row[local][k], s_wa[k * 64 + lane], acc);
            yh[((size_t)node << 6) + lane] = (_Float16)acc;
        }
    }
}

// ------- per-bucket counting sort -> per-node CSR (col, rp) ----------------
__global__ __launch_bounds__(256)
void csr_sort_kernel(const unsigned* __restrict__ pairs, const int* __restrict__ bsum,
                     int* __restrict__ col, int* __restrict__ rp,
                     int N, int E, int nbuckUsed) {
    __shared__ int cnt[256];
    __shared__ int cur[256];
    const int u = blockIdx.x, tid = threadIdx.x;
    const int base = bsum[u];
    const int end  = (u == NBUCK - 1) ? E : bsum[u + 1];
    const int node0 = u << 8;
    const int rows = min(256, N - node0);

    cnt[tid] = 0;
    __syncthreads();
    for (int e = base + tid; e < end; e += 256)
        atomicAdd(&cnt[pairs[e] >> 24], 1);
    __syncthreads();
    int own = cnt[tid];
    __syncthreads();
    cnt[tid] = own;
    __syncthreads();
    for (int off = 1; off < 256; off <<= 1) {
        int t = (tid >= off) ? cnt[tid - off] : 0;
        __syncthreads();
        cnt[tid] += t;
        __syncthreads();
    }
    const int excl = cnt[tid] - own;
    if (tid < rows) rp[node0 + tid] = base + excl;
    if (tid == 0 && u == nbuckUsed - 1) rp[N] = E;
    cur[tid] = base + excl;
    __syncthreads();
    for (int e = base + tid; e < end; e += 256) {
        unsigned p = pairs[e];
        int pos = atomicAdd(&cur[p >> 24], 1);
        col[pos] = (int)(p & 0xFFFFFF);
    }
}

// ---- FUSED layer: gather-agg + BN + ReLU -> LDS t-tile -> MFMA MLP --------
// Wave = 16-node tile (exactly 1 tile/wave at grid 1563). Gather: 4 passes x
// (4 nodes x 16 lanes, 8B/lane, 8-deep). MFMA: A-frags from wave-private LDS
// tile, weights pre-fragmented in VGPRs, z relayout C->A via second LDS tile.
// C/D layout: col=lane&15, row=(lane>>4)*4+reg.
template<bool LAST>
__global__ __launch_bounds__(256, 3)
void layer_kernel(const _Float16* __restrict__ yh,  // [(n+1),64] in (pad row n)
                  const int* __restrict__ rp, const int* __restrict__ col,
                  const float* __restrict__ ba,
                  const float* __restrict__ gam, const float* __restrict__ bet,
                  const float* __restrict__ rm, const float* __restrict__ rv,
                  const _Float16* __restrict__ fwb,  // [8][64][8] frag
                  const float* __restrict__ bb,
                  const _Float16* __restrict__ fwn,  // [8][64][8] frag
                  _Float16* __restrict__ outh,       // [n,64] out
                  int n) {
    __shared__ _Float16 tt[4][16][72];   // per-wave t tile
    __shared__ _Float16 zt[4][16][72];   // per-wave z tile

    const int tid  = threadIdx.x;
    const int lane = tid & 63;
    const int w    = tid >> 6;
    const int half = lane >> 4;    // gather group / k-group / row-group
    const int sub  = lane & 15;    // gather lane / A row / C col
    const int fo   = sub << 2;     // gather feature offset (4 feats/lane)

    half8v wbf[2][4];
    #pragma unroll
    for (int kk = 0; kk < 2; ++kk)
        #pragma unroll
        for (int nt = 0; nt < 4; ++nt)
            wbf[kk][nt] = *(const half8v*)&fwb[(((size_t)(kk * 4 + nt)) * 64 + lane) * 8];
    half8v wnf[LAST ? 1 : 2][4];
    if (!LAST) {
        #pragma unroll
        for (int kk = 0; kk < 2; ++kk)
            #pragma unroll
            for (int nt = 0; nt < 4; ++nt)
                wnf[kk][nt] = *(const half8v*)&fwn[(((size_t)(kk * 4 + nt)) * 64 + lane) * 8];
    }
    float bbr[4];
    #pragma unroll
    for (int nt = 0; nt < 4; ++nt) bbr[nt] = bb[nt * 16 + sub];

    const float4 g4 = *(const float4*)&gam[fo];
    const float4 v4 = *(const float4*)&rv[fo];
    const float4 b4 = *(const float4*)&bet[fo];
    const float4 m4 = *(const float4*)&rm[fo];
    const float4 ba4 = *(const float4*)&ba[fo];
    const float s0 = g4.x * rsqrtf(v4.x + BN_EPS);
    const float s1 = g4.y * rsqrtf(v4.y + BN_EPS);
    const float s2 = g4.z * rsqrtf(v4.z + BN_EPS);
    const float s3 = g4.w * rsqrtf(v4.w + BN_EPS);
    const float h0 = b4.x - m4.x * s0 + ba4.x * s0;
    const float h1 = b4.y - m4.y * s1 + ba4.y * s1;
    const float h2 = b4.z - m4.z * s2 + ba4.z * s2;
    const float h3 = b4.w - m4.w * s3 + ba4.w * s3;

    const int ntiles = (n + 15) >> 4;
    const int stride = gridDim.x * 4;
    for (int tile = blockIdx.x * 4 + w; tile < ntiles; tile += stride) {
        const int node0 = tile << 4;

        // ---- gather-agg phase: 4 passes of 4 nodes ----
        for (int p = 0; p < 4; ++p) {
            const int r = p * 4 + half;            // local row 0..15
            const int node = node0 + r;
            const bool ok = (node < n);
            const int nodeg = ok ? node : n;       // pad row if OOB
            const int beg = ok ? rp[node] : 0;
            const int end = ok ? rp[node + 1] : 0;

            half4v selfv = *(const half4v*)&yh[((size_t)nodeg << 6) + fo];
            float a0 = (float)selfv[0], a1 = (float)selfv[1];
            float a2 = (float)selfv[2], a3 = (float)selfv[3];

            for (int i = beg; i < end; i += 8) {
                int c[8];
                half4v v[8];
                #pragma unroll
                for (int j = 0; j < 8; ++j) c[j] = (i + j < end) ? col[i + j] : n;
                #pragma unroll
                for (int j = 0; j < 8; ++j)
                    v[j] = *(const half4v*)&yh[((size_t)c[j] << 6) + fo];
                #pragma unroll
                for (int j = 0; j < 8; ++j) {
                    a0 += (float)v[j][0];
                    a1 += (float)v[j][1];
                    a2 += (float)v[j][2];
                    a3 += (float)v[j][3];
                }
            }
            half4v o;
            o[0] = (_Float16)fmaxf(fmaf(a0, s0, h0), 0.f);
            o[1] = (_Float16)fmaxf(fmaf(a1, s1, h1), 0.f);
            o[2] = (_Float16)fmaxf(fmaf(a2, s2, h2), 0.f);
            o[3] = (_Float16)fmaxf(fmaf(a3, s3, h3), 0.f);
            *(half4v*)&tt[w][r][fo] = o;
        }
        asm volatile("s_waitcnt lgkmcnt(0)" ::: "memory");
        __builtin_amdgcn_sched_barrier(0);

        // ---- MFMA phase ----
        half8v at[2];
        #pragma unroll
        for (int kk = 0; kk < 2; ++kk)
            at[kk] = *(const half8v*)&tt[w][sub][kk * 32 + half * 8];

        float4v accz[4];
        #pragma unroll
        for (int nt = 0; nt < 4; ++nt) {
            float4v c = {0.f, 0.f, 0.f, 0.f};
            c = __builtin_amdgcn_mfma_f32_16x16x32_f16(at[0], wbf[0][nt], c, 0, 0, 0);
            c = __builtin_amdgcn_mfma_f32_16x16x32_f16(at[1], wbf[1][nt], c, 0, 0, 0);
            accz[nt] = c;
        }

        if (LAST) {
            #pragma unroll
            for (int nt = 0; nt < 4; ++nt)
                #pragma unroll
                for (int r = 0; r < 4; ++r) {
                    int m = node0 + half * 4 + r;
                    if (m < n)
                        outh[((size_t)m << 6) + nt * 16 + sub] =
                            (_Float16)fmaxf(accz[nt][r] + bbr[nt], 0.f);
                }
        } else {
            #pragma unroll
            for (int nt = 0; nt < 4; ++nt)
                #pragma unroll
                for (int r = 0; r < 4; ++r)
                    zt[w][half * 4 + r][nt * 16 + sub] =
                        (_Float16)fmaxf(accz[nt][r] + bbr[nt], 0.f);
            asm volatile("s_waitcnt lgkmcnt(0)" ::: "memory");
            __builtin_amdgcn_sched_barrier(0);
            half8v az[2];
            #pragma unroll
            for (int kk = 0; kk < 2; ++kk)
                az[kk] = *(const half8v*)&zt[w][sub][kk * 32 + half * 8];

            #pragma unroll
            for (int nt = 0; nt < 4; ++nt) {
                float4v c = {0.f, 0.f, 0.f, 0.f};
                c = __builtin_amdgcn_mfma_f32_16x16x32_f16(az[0], wnf[0][nt], c, 0, 0, 0);
                c = __builtin_amdgcn_mfma_f32_16x16x32_f16(az[1], wnf[1][nt], c, 0, 0, 0);
                #pragma unroll
                for (int r = 0; r < 4; ++r) {
                    int m = node0 + half * 4 + r;
                    if (m < n)
                        outh[((size_t)m << 6) + nt * 16 + sub] = (_Float16)c[r];
                }
            }
        }
    }
}

// ------- fused pool+head: block = graph; pool rows (8-deep), head math -----
__global__ __launch_bounds__(64)
void pool_head_kernel(const _Float16* __restrict__ h, const int* __restrict__ gptr,
                      const float* __restrict__ lw1, const float* __restrict__ lb1,
                      const float* __restrict__ lw2, const float* __restrict__ lb2,
                      float* __restrict__ out, int G) {
    __shared__ float s_row[64];
    const int g = blockIdx.x;
    if (g >= G) return;
    const int d = threadIdx.x;
    const int beg = gptr[g], end = gptr[g + 1];

    float acc = 0.f;
    int i = beg;
    const int end8 = beg + ((end - beg) & ~7);
    for (; i < end8; i += 8) {
        float v[8];
        #pragma unroll
        for (int j = 0; j < 8; ++j)
            v[j] = (float)h[((size_t)(i + j) << 6) + d];
        #pragma unroll
        for (int j = 0; j < 8; ++j) acc += v[j];
    }
    for (; i < end; ++i) acc += (float)h[((size_t)i << 6) + d];

    s_row[d] = acc;
    __syncthreads();

    float z = lb1[d];
    #pragma unroll 8
    for (int k = 0; k < 64; ++k)
        z = fmaf(s_row[k], lw1[k * 64 + d], z);
    z = fmaxf(z, 0.f);
    float r = z * lw2[d];
    #pragma unroll
    for (int off = 32; off > 0; off >>= 1)
        r += __shfl_down(r, off, 64);
    if (d == 0) out[g] = r + lb2[0];
}

extern "C" void kernel_launch(void* const* d_in, const int* in_sizes, int n_in,
                              void* d_out, int out_size, void* d_ws, size_t ws_size,
                              hipStream_t stream) {
    const float* x    = (const float*)d_in[0];
    const int* ei     = (const int*)d_in[1];
    const int* batch  = (const int*)d_in[2];
    const int N = in_sizes[0] / 11;
    const int E = in_sizes[1] / 2;
    const int G = out_size;
    const int* src = ei;
    const int* dst = ei + E;

    const float* p[28];
    for (int i = 0; i < 28; ++i) p[i] = (const float*)d_in[3 + i];
    // p[0..7]=L1 {wa,ba,g,be,m,v,wb,bb}, p[8..15]=L2, p[16..23]=L3
    // p[24]=lw1 p[25]=lb1 p[26]=lw2 p[27]=lb2

    _Float16* yA  = (_Float16*)d_ws;                     // [(N+1),64] fp16
    _Float16* yB  = yA + ((size_t)N + 1) * 64;           // [(N+1),64] fp16
    _Float16* fw  = yB + ((size_t)N + 1) * 64;           // [5*4096] weight frags
    int*   ghist  = (int*)(fw + 5 * 4096);               // [NBUCK*NBLK]
    int*   bsum   = ghist + NBUCK * NBLK;                // [512]
    int*   rp     = bsum + 512;                          // [N+1]
    int*   gptr   = rp + N + 1;                          // [G+1]
    int*   col    = gptr + G + 1;                        // [E]
    unsigned* pairs = (unsigned*)(col + E);              // [E] packed

    const int chunk     = (E + NBLK - 1) / NBLK;
    const int nscan     = NBUCK * NBLK;
    const int nbScanB   = nscan / 256;                   // 512
    const int nbuckUsed = (N + 255) >> 8;                // 391
    const int nGptrBlocks = (N + 255) / 256;             // 391
    const int ntiles    = (N + 15) >> 4;                 // 6250
    const int nbLayer   = (ntiles + 3) / 4;              // 1563: 1 tile/wave

    _Float16* fwb1 = fw;                 // L1 wb
    _Float16* fwn1 = fw + 4096;          // L2 wa
    _Float16* fwb2 = fw + 2 * 4096;      // L2 wb
    _Float16* fwn2 = fw + 3 * 4096;      // L3 wa
    _Float16* fwb3 = fw + 4 * 4096;      // L3 wb

    // ---- setup: hist || wfrag || gptr (one dispatch) ----
    setup_kernel<<<NBLK + 5 + nGptrBlocks, 256, 0, stream>>>(
        dst, ghist, E, chunk,
        yA + (size_t)N * 64, yB + (size_t)N * 64,
        batch, gptr, N, G,
        p[6], p[8], p[14], p[16], p[22], fw);

    // ---- CSR build (pre-transform hidden under bin_fill) ----
    scan_block_g<<<nbScanB, 256, 0, stream>>>(ghist, bsum, nscan);
    scan_top_kernel<<<1, 512, 0, stream>>>(bsum, nbScanB);
    fill_pre_kernel<<<NBLK + 390, 256, 0, stream>>>(src, dst, ghist, bsum,
        pairs, E, chunk, x, p[0], yA, N);
    csr_sort_kernel<<<nbuckUsed, 256, 0, stream>>>(pairs, bsum, col, rp, N, E, nbuckUsed);

    // ---- fused layers (ping-pong yA <-> yB) ----
    layer_kernel<false><<<nbLayer, 256, 0, stream>>>(yA, rp, col,
        p[1], p[2], p[3], p[4], p[5], fwb1, p[7], fwn1, yB, N);
    layer_kernel<false><<<nbLayer, 256, 0, stream>>>(yB, rp, col,
        p[9], p[10], p[11], p[12], p[13], fwb2, p[15], fwn2, yA, N);
    layer_kernel<true><<<nbLayer, 256, 0, stream>>>(yA, rp, col,
        p[17], p[18], p[19], p[20], p[21], fwb3, p[23], nullptr, yB, N);

    // ---- fused pool + head ----
    pool_head_kernel<<<G, 64, 0, stream>>>(yB, gptr,
        p[24], p[25], p[26], p[27], (float*)d_out, G);
}

// Round 18
// 157.771 us; speedup vs baseline: 1.0978x; 1.0978x over previous
//
#include <hip/hip_runtime.h>

// GIN forward: transformed-space linearity (y = h@wa; agg@wa = y_self + sum y_nbr)
// fp16 ping-pong activation tables, CSR via bucket binning + packed counting
// sort (pre-transform hidden under bin_fill, 2048-block role split), FUSED
// per-layer kernel: 4-node/16-lane gather agg (8-deep) + BN/ReLU ->
// wave-private LDS t-tile -> MFMA-f16 MLP (weights pre-fragmented in VGPRs)
// -> y' store; 1 tile/wave. Per-graph fused pool+head.
// N=100000, E=1200000, DIM=64, G=1000, IN=11.

#define BN_EPS 1e-5f
#define NBUCK 512
#define NBLK  256

typedef __attribute__((ext_vector_type(8))) _Float16 half8v;  // 8 f16 (4 VGPRs)
typedef __attribute__((ext_vector_type(4))) _Float16 half4v;  // 4 f16 (2 VGPRs)
typedef __attribute__((ext_vector_type(4))) float float4v;    // 4 fp32 acc

// ---- setup: [0,256) hist+zero pad rows, [256,261) wfrag, [261,261+GB) gptr -
__global__ __launch_bounds__(256)
void setup_kernel(const int* __restrict__ dst, int* __restrict__ ghist,
                  int E, int chunk,
                  _Float16* __restrict__ padA, _Float16* __restrict__ padB,
                  const int* __restrict__ batch, int* __restrict__ gptr,
                  int N, int G,
                  const float* __restrict__ w0, const float* __restrict__ w1,
                  const float* __restrict__ w2, const float* __restrict__ w3,
                  const float* __restrict__ w4, _Float16* __restrict__ fwout) {
    __shared__ int h[NBUCK];
    const int blk = blockIdx.x, tid = threadIdx.x;

    if (blk < NBLK) {
        if (blk == 0 && tid < 64) {
            padA[tid] = (_Float16)0.f;
            padB[tid] = (_Float16)0.f;
        }
        for (int u = tid; u < NBUCK; u += 256) h[u] = 0;
        __syncthreads();
        const int e0 = blk * chunk, e1 = min(E, e0 + chunk);
        for (int e = e0 + tid; e < e1; e += 256)
            atomicAdd(&h[dst[e] >> 8], 1);
        __syncthreads();
        for (int u = tid; u < NBUCK; u += 256)
            ghist[u * NBLK + blk] = h[u];
    } else if (blk < NBLK + 5) {
        const int m = blk - NBLK;
        const float* w = (m == 0) ? w0 : (m == 1) ? w1 : (m == 2) ? w2 :
                         (m == 3) ? w3 : w4;
        _Float16* o = fwout + (size_t)m * 4096;
        const int lane = tid & 63;
        const int cb   = tid >> 6;
        const int half = lane >> 4, sub = lane & 15;
        #pragma unroll
        for (int it = 0; it < 2; ++it) {
            int c = cb + 4 * it;             // 0..7 = kk*4 + nt
            int kk = c >> 2, nt = c & 3;
            _Float16 f[8];
            #pragma unroll
            for (int j = 0; j < 8; ++j)
                f[j] = (_Float16)w[(kk * 32 + half * 8 + j) * 64 + nt * 16 + sub];
            *(half8v*)&o[((size_t)c * 64 + lane) * 8] = *(half8v*)f;
        }
    } else {
        int i = (blk - NBLK - 5) * 256 + tid;
        if (i < N) {
            int b = batch[i];
            int bprev = (i == 0) ? -1 : batch[i - 1];
            for (int g = bprev + 1; g <= b; ++g) gptr[g] = i;
            if (i == N - 1)
                for (int g = b + 1; g <= G; ++g) gptr[g] = N;
        }
    }
}

// ---------------- hierarchical exclusive scan ------------------------------
__global__ __launch_bounds__(256)
void scan_block_g(int* __restrict__ a, int* __restrict__ bsum, int n) {
    __shared__ int s[256];
    int i = blockIdx.x * 256 + threadIdx.x;
    int v = (i < n) ? a[i] : 0;
    s[threadIdx.x] = v;
    __syncthreads();
    for (int off = 1; off < 256; off <<= 1) {
        int t = (threadIdx.x >= off) ? s[threadIdx.x - off] : 0;
        __syncthreads();
        s[threadIdx.x] += t;
        __syncthreads();
    }
    if (i < n) a[i] = s[threadIdx.x] - v;
    if (threadIdx.x == 255) bsum[blockIdx.x] = s[255];
}

__global__ __launch_bounds__(512)
void scan_top_kernel(int* bsum, int nb) {
    __shared__ int s[512];
    int v = (threadIdx.x < nb) ? bsum[threadIdx.x] : 0;
    s[threadIdx.x] = v;
    __syncthreads();
    for (int off = 1; off < 512; off <<= 1) {
        int t = (threadIdx.x >= off) ? s[threadIdx.x - off] : 0;
        __syncthreads();
        s[threadIdx.x] += t;
        __syncthreads();
    }
    if (threadIdx.x < nb) bsum[threadIdx.x] = s[threadIdx.x] - v;
}

// ---- bin fill + pre-transform (role-split, independent work) --------------
// blocks [0,NBLK): clustered packed pair writes via block-local LDS cursors
// blocks [NBLK, 2048): yh = f16(x @ w1a)  (1792 blocks, ~14 groups each)
// packed pair: (dstLocal << 24) | src   (src < 2^24)
__global__ __launch_bounds__(256)
void fill_pre_kernel(const int* __restrict__ src, const int* __restrict__ dst,
                     const int* __restrict__ ghist, const int* __restrict__ bsum,
                     unsigned* __restrict__ pairs, int E, int chunk,
                     const float* __restrict__ x, const float* __restrict__ wa,
                     _Float16* __restrict__ yh, int n) {
    __shared__ int cur[NBUCK];
    __shared__ float s_wa[11 * 64];
    __shared__ float s_row[4][11];
    const int tid = threadIdx.x, blk = blockIdx.x;

    if (blk < NBLK) {
        // ---- bin fill ----
        for (int u = tid; u < NBUCK; u += 256)
            cur[u] = ghist[u * NBLK + blk] + bsum[u];
        __syncthreads();
        const int e0 = blk * chunk, e1 = min(E, e0 + chunk);
        for (int e = e0 + tid; e < e1; e += 256) {
            int d = dst[e];
            int pos = atomicAdd(&cur[d >> 8], 1);
            pairs[pos] = ((unsigned)(d & 255) << 24) | (unsigned)src[e];
        }
    } else {
        // ---- pre-transform ----
        const int pb = blk - NBLK;
        const int nPre = gridDim.x - NBLK;
        const int lane = tid & 63;
        const int local = tid >> 6;
        for (int i = tid; i < 11 * 64; i += 256) s_wa[i] = wa[i];
        __syncthreads();
        const int groups = (n + 3) >> 2;
        for (int grp = pb; grp < groups; grp += nPre) {
            const int node = grp * 4 + local;
            if (node >= n) continue;
            if (lane < 11) s_row[local][lane] = x[(size_t)node * 11 + lane];
            float acc = 0.f;
            #pragma unroll
            for (int k = 0; k < 11; ++k)
                acc = fmaf(s_row[local][k], s_wa[k * 64 + lane], acc);
            yh[((size_t)node << 6) + lane] = (_Float16)acc;
        }
    }
}

// ------- per-bucket counting sort -> per-node CSR (col, rp) ----------------
__global__ __launch_bounds__(256)
void csr_sort_kernel(const unsigned* __restrict__ pairs, const int* __restrict__ bsum,
                     int* __restrict__ col, int* __restrict__ rp,
                     int N, int E, int nbuckUsed) {
    __shared__ int cnt[256];
    __shared__ int cur[256];
    const int u = blockIdx.x, tid = threadIdx.x;
    const int base = bsum[u];
    const int end  = (u == NBUCK - 1) ? E : bsum[u + 1];
    const int node0 = u << 8;
    const int rows = min(256, N - node0);

    cnt[tid] = 0;
    __syncthreads();
    for (int e = base + tid; e < end; e += 256)
        atomicAdd(&cnt[pairs[e] >> 24], 1);
    __syncthreads();
    int own = cnt[tid];
    __syncthreads();
    cnt[tid] = own;
    __syncthreads();
    for (int off = 1; off < 256; off <<= 1) {
        int t = (tid >= off) ? cnt[tid - off] : 0;
        __syncthreads();
        cnt[tid] += t;
        __syncthreads();
    }
    const int excl = cnt[tid] - own;
    if (tid < rows) rp[node0 + tid] = base + excl;
    if (tid == 0 && u == nbuckUsed - 1) rp[N] = E;
    cur[tid] = base + excl;
    __syncthreads();
    for (int e = base + tid; e < end; e += 256) {
        unsigned p = pairs[e];
        int pos = atomicAdd(&cur[p >> 24], 1);
        col[pos] = (int)(p & 0xFFFFFF);
    }
}

// ---- FUSED layer: gather-agg + BN + ReLU -> LDS t-tile -> MFMA MLP --------
// Wave = 16-node tile (exactly 1 tile/wave at grid 1563). Gather: 4 passes x
// (4 nodes x 16 lanes, 8B/lane, 8-deep). MFMA: A-frags from wave-private LDS
// tile, weights pre-fragmented in VGPRs, z relayout C->A via second LDS tile.
// C/D layout: col=lane&15, row=(lane>>4)*4+reg.
template<bool LAST>
__global__ __launch_bounds__(256, 3)
void layer_kernel(const _Float16* __restrict__ yh,  // [(n+1),64] in (pad row n)
                  const int* __restrict__ rp, const int* __restrict__ col,
                  const float* __restrict__ ba,
                  const float* __restrict__ gam, const float* __restrict__ bet,
                  const float* __restrict__ rm, const float* __restrict__ rv,
                  const _Float16* __restrict__ fwb,  // [8][64][8] frag
                  const float* __restrict__ bb,
                  const _Float16* __restrict__ fwn,  // [8][64][8] frag
                  _Float16* __restrict__ outh,       // [n,64] out
                  int n) {
    __shared__ _Float16 tt[4][16][72];   // per-wave t tile
    __shared__ _Float16 zt[4][16][72];   // per-wave z tile

    const int tid  = threadIdx.x;
    const int lane = tid & 63;
    const int w    = tid >> 6;
    const int half = lane >> 4;    // gather group / k-group / row-group
    const int sub  = lane & 15;    // gather lane / A row / C col
    const int fo   = sub << 2;     // gather feature offset (4 feats/lane)

    half8v wbf[2][4];
    #pragma unroll
    for (int kk = 0; kk < 2; ++kk)
        #pragma unroll
        for (int nt = 0; nt < 4; ++nt)
            wbf[kk][nt] = *(const half8v*)&fwb[(((size_t)(kk * 4 + nt)) * 64 + lane) * 8];
    half8v wnf[LAST ? 1 : 2][4];
    if (!LAST) {
        #pragma unroll
        for (int kk = 0; kk < 2; ++kk)
            #pragma unroll
            for (int nt = 0; nt < 4; ++nt)
                wnf[kk][nt] = *(const half8v*)&fwn[(((size_t)(kk * 4 + nt)) * 64 + lane) * 8];
    }
    float bbr[4];
    #pragma unroll
    for (int nt = 0; nt < 4; ++nt) bbr[nt] = bb[nt * 16 + sub];

    const float4 g4 = *(const float4*)&gam[fo];
    const float4 v4 = *(const float4*)&rv[fo];
    const float4 b4 = *(const float4*)&bet[fo];
    const float4 m4 = *(const float4*)&rm[fo];
    const float4 ba4 = *(const float4*)&ba[fo];
    const float s0 = g4.x * rsqrtf(v4.x + BN_EPS);
    const float s1 = g4.y * rsqrtf(v4.y + BN_EPS);
    const float s2 = g4.z * rsqrtf(v4.z + BN_EPS);
    const float s3 = g4.w * rsqrtf(v4.w + BN_EPS);
    const float h0 = b4.x - m4.x * s0 + ba4.x * s0;
    const float h1 = b4.y - m4.y * s1 + ba4.y * s1;
    const float h2 = b4.z - m4.z * s2 + ba4.z * s2;
    const float h3 = b4.w - m4.w * s3 + ba4.w * s3;

    const int ntiles = (n + 15) >> 4;
    const int stride = gridDim.x * 4;
    for (int tile = blockIdx.x * 4 + w; tile < ntiles; tile += stride) {
        const int node0 = tile << 4;

        // ---- gather-agg phase: 4 passes of 4 nodes ----
        for (int p = 0; p < 4; ++p) {
            const int r = p * 4 + half;            // local row 0..15
            const int node = node0 + r;
            const bool ok = (node < n);
            const int nodeg = ok ? node : n;       // pad row if OOB
            const int beg = ok ? rp[node] : 0;
            const int end = ok ? rp[node + 1] : 0;

            half4v selfv = *(const half4v*)&yh[((size_t)nodeg << 6) + fo];
            float a0 = (float)selfv[0], a1 = (float)selfv[1];
            float a2 = (float)selfv[2], a3 = (float)selfv[3];

            for (int i = beg; i < end; i += 8) {
                int c[8];
                half4v v[8];
                #pragma unroll
                for (int j = 0; j < 8; ++j) c[j] = (i + j < end) ? col[i + j] : n;
                #pragma unroll
                for (int j = 0; j < 8; ++j)
                    v[j] = *(const half4v*)&yh[((size_t)c[j] << 6) + fo];
                #pragma unroll
                for (int j = 0; j < 8; ++j) {
                    a0 += (float)v[j][0];
                    a1 += (float)v[j][1];
                    a2 += (float)v[j][2];
                    a3 += (float)v[j][3];
                }
            }
            half4v o;
            o[0] = (_Float16)fmaxf(fmaf(a0, s0, h0), 0.f);
            o[1] = (_Float16)fmaxf(fmaf(a1, s1, h1), 0.f);
            o[2] = (_Float16)fmaxf(fmaf(a2, s2, h2), 0.f);
            o[3] = (_Float16)fmaxf(fmaf(a3, s3, h3), 0.f);
            *(half4v*)&tt[w][r][fo] = o;
        }
        asm volatile("s_waitcnt lgkmcnt(0)" ::: "memory");
        __builtin_amdgcn_sched_barrier(0);

        // ---- MFMA phase ----
        half8v at[2];
        #pragma unroll
        for (int kk = 0; kk < 2; ++kk)
            at[kk] = *(const half8v*)&tt[w][sub][kk * 32 + half * 8];

        float4v accz[4];
        #pragma unroll
        for (int nt = 0; nt < 4; ++nt) {
            float4v c = {0.f, 0.f, 0.f, 0.f};
            c = __builtin_amdgcn_mfma_f32_16x16x32_f16(at[0], wbf[0][nt], c, 0, 0, 0);
            c = __builtin_amdgcn_mfma_f32_16x16x32_f16(at[1], wbf[1][nt], c, 0, 0, 0);
            accz[nt] = c;
        }

        if (LAST) {
            #pragma unroll
            for (int nt = 0; nt < 4; ++nt)
                #pragma unroll
                for (int r = 0; r < 4; ++r) {
                    int m = node0 + half * 4 + r;
                    if (m < n)
                        outh[((size_t)m << 6) + nt * 16 + sub] =
                            (_Float16)fmaxf(accz[nt][r] + bbr[nt], 0.f);
                }
        } else {
            #pragma unroll
            for (int nt = 0; nt < 4; ++nt)
                #pragma unroll
                for (int r = 0; r < 4; ++r)
                    zt[w][half * 4 + r][nt * 16 + sub] =
                        (_Float16)fmaxf(accz[nt][r] + bbr[nt], 0.f);
            asm volatile("s_waitcnt lgkmcnt(0)" ::: "memory");
            __builtin_amdgcn_sched_barrier(0);
            half8v az[2];
            #pragma unroll
            for (int kk = 0; kk < 2; ++kk)
                az[kk] = *(const half8v*)&zt[w][sub][kk * 32 + half * 8];

            #pragma unroll
            for (int nt = 0; nt < 4; ++nt) {
                float4v c = {0.f, 0.f, 0.f, 0.f};
                c = __builtin_amdgcn_mfma_f32_16x16x32_f16(az[0], wnf[0][nt], c, 0, 0, 0);
                c = __builtin_amdgcn_mfma_f32_16x16x32_f16(az[1], wnf[1][nt], c, 0, 0, 0);
                #pragma unroll
                for (int r = 0; r < 4; ++r) {
                    int m = node0 + half * 4 + r;
                    if (m < n)
                        outh[((size_t)m << 6) + nt * 16 + sub] = (_Float16)c[r];
                }
            }
        }
    }
}

// ------- fused pool+head: block = graph; pool rows (8-deep), head math -----
__global__ __launch_bounds__(64)
void pool_head_kernel(const _Float16* __restrict__ h, const int* __restrict__ gptr,
                      const float* __restrict__ lw1, const float* __restrict__ lb1,
                      const float* __restrict__ lw2, const float* __restrict__ lb2,
                      float* __restrict__ out, int G) {
    __shared__ float s_row[64];
    const int g = blockIdx.x;
    if (g >= G) return;
    const int d = threadIdx.x;
    const int beg = gptr[g], end = gptr[g + 1];

    float acc = 0.f;
    int i = beg;
    const int end8 = beg + ((end - beg) & ~7);
    for (; i < end8; i += 8) {
        float v[8];
        #pragma unroll
        for (int j = 0; j < 8; ++j)
            v[j] = (float)h[((size_t)(i + j) << 6) + d];
        #pragma unroll
        for (int j = 0; j < 8; ++j) acc += v[j];
    }
    for (; i < end; ++i) acc += (float)h[((size_t)i << 6) + d];

    s_row[d] = acc;
    __syncthreads();

    float z = lb1[d];
    #pragma unroll 8
    for (int k = 0; k < 64; ++k)
        z = fmaf(s_row[k], lw1[k * 64 + d], z);
    z = fmaxf(z, 0.f);
    float r = z * lw2[d];
    #pragma unroll
    for (int off = 32; off > 0; off >>= 1)
        r += __shfl_down(r, off, 64);
    if (d == 0) out[g] = r + lb2[0];
}

extern "C" void kernel_launch(void* const* d_in, const int* in_sizes, int n_in,
                              void* d_out, int out_size, void* d_ws, size_t ws_size,
                              hipStream_t stream) {
    const float* x    = (const float*)d_in[0];
    const int* ei     = (const int*)d_in[1];
    const int* batch  = (const int*)d_in[2];
    const int N = in_sizes[0] / 11;
    const int E = in_sizes[1] / 2;
    const int G = out_size;
    const int* src = ei;
    const int* dst = ei + E;

    const float* p[28];
    for (int i = 0; i < 28; ++i) p[i] = (const float*)d_in[3 + i];
    // p[0..7]=L1 {wa,ba,g,be,m,v,wb,bb}, p[8..15]=L2, p[16..23]=L3
    // p[24]=lw1 p[25]=lb1 p[26]=lw2 p[27]=lb2

    _Float16* yA  = (_Float16*)d_ws;                     // [(N+1),64] fp16
    _Float16* yB  = yA + ((size_t)N + 1) * 64;           // [(N+1),64] fp16
    _Float16* fw  = yB + ((size_t)N + 1) * 64;           // [5*4096] weight frags
    int*   ghist  = (int*)(fw + 5 * 4096);               // [NBUCK*NBLK]
    int*   bsum   = ghist + NBUCK * NBLK;                // [512]
    int*   rp     = bsum + 512;                          // [N+1]
    int*   gptr   = rp + N + 1;                          // [G+1]
    int*   col    = gptr + G + 1;                        // [E]
    unsigned* pairs = (unsigned*)(col + E);              // [E] packed

    const int chunk     = (E + NBLK - 1) / NBLK;
    const int nscan     = NBUCK * NBLK;
    const int nbScanB   = nscan / 256;                   // 512
    const int nbuckUsed = (N + 255) >> 8;                // 391
    const int nGptrBlocks = (N + 255) / 256;             // 391
    const int ntiles    = (N + 15) >> 4;                 // 6250
    const int nbLayer   = (ntiles + 3) / 4;              // 1563: 1 tile/wave

    _Float16* fwb1 = fw;                 // L1 wb
    _Float16* fwn1 = fw + 4096;          // L2 wa
    _Float16* fwb2 = fw + 2 * 4096;      // L2 wb
    _Float16* fwn2 = fw + 3 * 4096;      // L3 wa
    _Float16* fwb3 = fw + 4 * 4096;      // L3 wb

    // ---- setup: hist || wfrag || gptr (one dispatch) ----
    setup_kernel<<<NBLK + 5 + nGptrBlocks, 256, 0, stream>>>(
        dst, ghist, E, chunk,
        yA + (size_t)N * 64, yB + (size_t)N * 64,
        batch, gptr, N, G,
        p[6], p[8], p[14], p[16], p[22], fw);

    // ---- CSR build (pre-transform hidden under bin_fill; 1792 pre blocks) --
    scan_block_g<<<nbScanB, 256, 0, stream>>>(ghist, bsum, nscan);
    scan_top_kernel<<<1, 512, 0, stream>>>(bsum, nbScanB);
    fill_pre_kernel<<<2048, 256, 0, stream>>>(src, dst, ghist, bsum,
        pairs, E, chunk, x, p[0], yA, N);
    csr_sort_kernel<<<nbuckUsed, 256, 0, stream>>>(pairs, bsum, col, rp, N, E, nbuckUsed);

    // ---- fused layers (ping-pong yA <-> yB) ----
    layer_kernel<false><<<nbLayer, 256, 0, stream>>>(yA, rp, col,
        p[1], p[2], p[3], p[4], p[5], fwb1, p[7], fwn1, yB, N);
    layer_kernel<false><<<nbLayer, 256, 0, stream>>>(yB, rp, col,
        p[9], p[10], p[11], p[12], p[13], fwb2, p[15], fwn2, yA, N);
    layer_kernel<true><<<nbLayer, 256, 0, stream>>>(yA, rp, col,
        p[17], p[18], p[19], p[20], p[21], fwb3, p[23], nullptr, yB, N);

    // ---- fused pool + head ----
    pool_head_kernel<<<G, 64, 0, stream>>>(yB, gptr,
        p[24], p[25], p[26], p[27], (float*)d_out, G);
}

// Round 19
// 157.033 us; speedup vs baseline: 1.1029x; 1.0047x over previous
//
#include <hip/hip_runtime.h>

// GIN forward: transformed-space linearity (y = h@wa; agg@wa = y_self + sum y_nbr)
// fp16 ping-pong activation tables, CSR via bucket binning + packed counting
// sort (bucket bases re-derived locally in LDS; no top-scan dispatch;
// pre-transform hidden under bin_fill), FUSED per-layer kernel:
// 4-node/16-lane gather agg (8-deep) + BN/ReLU -> wave-private LDS t-tile ->
// MFMA-f16 MLP (weights pre-fragmented in VGPRs) -> y' store; 1 tile/wave.
// Per-graph fused pool+head (4 graphs/block).
// N=100000, E=1200000, DIM=64, G=1000, IN=11.

#define BN_EPS 1e-5f
#define NBUCK 512
#define NBLK  256

typedef __attribute__((ext_vector_type(8))) _Float16 half8v;  // 8 f16 (4 VGPRs)
typedef __attribute__((ext_vector_type(4))) _Float16 half4v;  // 4 f16 (2 VGPRs)
typedef __attribute__((ext_vector_type(4))) float float4v;    // 4 fp32 acc

// ---- setup: [0,256) hist+zero pad rows, [256,261) wfrag, [261,261+GB) gptr -
__global__ __launch_bounds__(256)
void setup_kernel(const int* __restrict__ dst, int* __restrict__ ghist,
                  int E, int chunk,
                  _Float16* __restrict__ padA, _Float16* __restrict__ padB,
                  const int* __restrict__ batch, int* __restrict__ gptr,
                  int N, int G,
                  const float* __restrict__ w0, const float* __restrict__ w1,
                  const float* __restrict__ w2, const float* __restrict__ w3,
                  const float* __restrict__ w4, _Float16* __restrict__ fwout) {
    __shared__ int h[NBUCK];
    const int blk = blockIdx.x, tid = threadIdx.x;

    if (blk < NBLK) {
        if (blk == 0 && tid < 64) {
            padA[tid] = (_Float16)0.f;
            padB[tid] = (_Float16)0.f;
        }
        for (int u = tid; u < NBUCK; u += 256) h[u] = 0;
        __syncthreads();
        const int e0 = blk * chunk, e1 = min(E, e0 + chunk);
        for (int e = e0 + tid; e < e1; e += 256)
            atomicAdd(&h[dst[e] >> 8], 1);
        __syncthreads();
        for (int u = tid; u < NBUCK; u += 256)
            ghist[u * NBLK + blk] = h[u];
    } else if (blk < NBLK + 5) {
        const int m = blk - NBLK;
        const float* w = (m == 0) ? w0 : (m == 1) ? w1 : (m == 2) ? w2 :
                         (m == 3) ? w3 : w4;
        _Float16* o = fwout + (size_t)m * 4096;
        const int lane = tid & 63;
        const int cb   = tid >> 6;
        const int half = lane >> 4, sub = lane & 15;
        #pragma unroll
        for (int it = 0; it < 2; ++it) {
            int c = cb + 4 * it;             // 0..7 = kk*4 + nt
            int kk = c >> 2, nt = c & 3;
            _Float16 f[8];
            #pragma unroll
            for (int j = 0; j < 8; ++j)
                f[j] = (_Float16)w[(kk * 32 + half * 8 + j) * 64 + nt * 16 + sub];
            *(half8v*)&o[((size_t)c * 64 + lane) * 8] = *(half8v*)f;
        }
    } else {
        int i = (blk - NBLK - 5) * 256 + tid;
        if (i < N) {
            int b = batch[i];
            int bprev = (i == 0) ? -1 : batch[i - 1];
            for (int g = bprev + 1; g <= b; ++g) gptr[g] = i;
            if (i == N - 1)
                for (int g = b + 1; g <= G; ++g) gptr[g] = N;
        }
    }
}

// ---------------- per-bucket scan (chunk = bucket's 256 block counts) ------
__global__ __launch_bounds__(256)
void scan_block_g(int* __restrict__ a, int* __restrict__ bsum, int n) {
    __shared__ int s[256];
    int i = blockIdx.x * 256 + threadIdx.x;
    int v = (i < n) ? a[i] : 0;
    s[threadIdx.x] = v;
    __syncthreads();
    for (int off = 1; off < 256; off <<= 1) {
        int t = (threadIdx.x >= off) ? s[threadIdx.x - off] : 0;
        __syncthreads();
        s[threadIdx.x] += t;
        __syncthreads();
    }
    if (i < n) a[i] = s[threadIdx.x] - v;
    if (threadIdx.x == 255) bsum[blockIdx.x] = s[255];
}

// ---- bin fill + pre-transform (role-split); bucket bases from local scan --
// blocks [0,NBLK): clustered packed pair writes via block-local LDS cursors
// blocks [NBLK, 2048): yh = f16(x @ w1a)
// packed pair: (dstLocal << 24) | src   (src < 2^24)
__global__ __launch_bounds__(256)
void fill_pre_kernel(const int* __restrict__ src, const int* __restrict__ dst,
                     const int* __restrict__ ghist, const int* __restrict__ bsumRaw,
                     unsigned* __restrict__ pairs, int E, int chunk,
                     const float* __restrict__ x, const float* __restrict__ wa,
                     _Float16* __restrict__ yh, int n) {
    __shared__ int cur[NBUCK];
    __shared__ int ps[256];
    __shared__ float s_wa[11 * 64];
    __shared__ float s_row[4][11];
    const int tid = threadIdx.x, blk = blockIdx.x;

    if (blk < NBLK) {
        // ---- local exclusive scan of bsumRaw[512] (pair per thread) ----
        int a0 = bsumRaw[2 * tid], a1 = bsumRaw[2 * tid + 1];
        ps[tid] = a0 + a1;
        __syncthreads();
        for (int off = 1; off < 256; off <<= 1) {
            int v = (tid >= off) ? ps[tid - off] : 0;
            __syncthreads();
            ps[tid] += v;
            __syncthreads();
        }
        const int pb = ps[tid] - (a0 + a1);
        cur[2 * tid]     = pb      + ghist[(2 * tid) * NBLK + blk];
        cur[2 * tid + 1] = pb + a0 + ghist[(2 * tid + 1) * NBLK + blk];
        __syncthreads();
        // ---- bin fill ----
        const int e0 = blk * chunk, e1 = min(E, e0 + chunk);
        for (int e = e0 + tid; e < e1; e += 256) {
            int d = dst[e];
            int pos = atomicAdd(&cur[d >> 8], 1);
            pairs[pos] = ((unsigned)(d & 255) << 24) | (unsigned)src[e];
        }
    } else {
        // ---- pre-transform ----
        const int pb = blk - NBLK;
        const int nPre = gridDim.x - NBLK;
        const int lane = tid & 63;
        const int local = tid >> 6;
        for (int i = tid; i < 11 * 64; i += 256) s_wa[i] = wa[i];
        __syncthreads();
        const int groups = (n + 3) >> 2;
        for (int grp = pb; grp < groups; grp += nPre) {
            const int node = grp * 4 + local;
            if (node >= n) continue;
            if (lane < 11) s_row[local][lane] = x[(size_t)node * 11 + lane];
            float acc = 0.f;
            #pragma unroll
            for (int k = 0; k < 11; ++k)
                acc = fmaf(s_row[local][k], s_wa[k * 64 + lane], acc);
            yh[((size_t)node << 6) + lane] = (_Float16)acc;
        }
    }
}

// ------- per-bucket counting sort -> per-node CSR (col, rp) ----------------
// bucket bases re-derived from raw bsum via local LDS scan.
__global__ __launch_bounds__(256)
void csr_sort_kernel(const unsigned* __restrict__ pairs, const int* __restrict__ bsumRaw,
                     int* __restrict__ col, int* __restrict__ rp,
                     int N, int E, int nbuckUsed) {
    __shared__ int sb[NBUCK + 1];
    __shared__ int cnt[256];
    __shared__ int cur[256];
    const int u = blockIdx.x, tid = threadIdx.x;
    // local exclusive scan of bsumRaw[512] -> bucket bases
    {
        int a0 = bsumRaw[2 * tid], a1 = bsumRaw[2 * tid + 1];
        cnt[tid] = a0 + a1;
        __syncthreads();
        for (int off = 1; off < 256; off <<= 1) {
            int v = (tid >= off) ? cnt[tid - off] : 0;
            __syncthreads();
            cnt[tid] += v;
            __syncthreads();
        }
        int pb = cnt[tid] - (a0 + a1);
        sb[2 * tid] = pb;
        sb[2 * tid + 1] = pb + a0;
        if (tid == 255) sb[NBUCK] = E;
        __syncthreads();
    }
    const int base = sb[u];
    const int end  = sb[u + 1];
    const int node0 = u << 8;
    const int rows = min(256, N - node0);

    cnt[tid] = 0;
    __syncthreads();
    for (int e = base + tid; e < end; e += 256)
        atomicAdd(&cnt[pairs[e] >> 24], 1);
    __syncthreads();
    int own = cnt[tid];
    __syncthreads();
    cnt[tid] = own;
    __syncthreads();
    for (int off = 1; off < 256; off <<= 1) {
        int t = (tid >= off) ? cnt[tid - off] : 0;
        __syncthreads();
        cnt[tid] += t;
        __syncthreads();
    }
    const int excl = cnt[tid] - own;
    if (tid < rows) rp[node0 + tid] = base + excl;
    if (tid == 0 && u == nbuckUsed - 1) rp[N] = E;
    cur[tid] = base + excl;
    __syncthreads();
    for (int e = base + tid; e < end; e += 256) {
        unsigned p = pairs[e];
        int pos = atomicAdd(&cur[p >> 24], 1);
        col[pos] = (int)(p & 0xFFFFFF);
    }
}

// ---- FUSED layer: gather-agg + BN + ReLU -> LDS t-tile -> MFMA MLP --------
// Wave = 16-node tile (exactly 1 tile/wave at grid 1563). Gather: 4 passes x
// (4 nodes x 16 lanes, 8B/lane, 8-deep). MFMA: A-frags from wave-private LDS
// tile, weights pre-fragmented in VGPRs, z relayout C->A via second LDS tile.
// C/D layout: col=lane&15, row=(lane>>4)*4+reg.
template<bool LAST>
__global__ __launch_bounds__(256, 3)
void layer_kernel(const _Float16* __restrict__ yh,  // [(n+1),64] in (pad row n)
                  const int* __restrict__ rp, const int* __restrict__ col,
                  const float* __restrict__ ba,
                  const float* __restrict__ gam, const float* __restrict__ bet,
                  const float* __restrict__ rm, const float* __restrict__ rv,
                  const _Float16* __restrict__ fwb,  // [8][64][8] frag
                  const float* __restrict__ bb,
                  const _Float16* __restrict__ fwn,  // [8][64][8] frag
                  _Float16* __restrict__ outh,       // [n,64] out
                  int n) {
    __shared__ _Float16 tt[4][16][72];   // per-wave t tile
    __shared__ _Float16 zt[4][16][72];   // per-wave z tile

    const int tid  = threadIdx.x;
    const int lane = tid & 63;
    const int w    = tid >> 6;
    const int half = lane >> 4;    // gather group / k-group / row-group
    const int sub  = lane & 15;    // gather lane / A row / C col
    const int fo   = sub << 2;     // gather feature offset (4 feats/lane)

    half8v wbf[2][4];
    #pragma unroll
    for (int kk = 0; kk < 2; ++kk)
        #pragma unroll
        for (int nt = 0; nt < 4; ++nt)
            wbf[kk][nt] = *(const half8v*)&fwb[(((size_t)(kk * 4 + nt)) * 64 + lane) * 8];
    half8v wnf[LAST ? 1 : 2][4];
    if (!LAST) {
        #pragma unroll
        for (int kk = 0; kk < 2; ++kk)
            #pragma unroll
            for (int nt = 0; nt < 4; ++nt)
                wnf[kk][nt] = *(const half8v*)&fwn[(((size_t)(kk * 4 + nt)) * 64 + lane) * 8];
    }
    float bbr[4];
    #pragma unroll
    for (int nt = 0; nt < 4; ++nt) bbr[nt] = bb[nt * 16 + sub];

    const float4 g4 = *(const float4*)&gam[fo];
    const float4 v4 = *(const float4*)&rv[fo];
    const float4 b4 = *(const float4*)&bet[fo];
    const float4 m4 = *(const float4*)&rm[fo];
    const float4 ba4 = *(const float4*)&ba[fo];
    const float s0 = g4.x * rsqrtf(v4.x + BN_EPS);
    const float s1 = g4.y * rsqrtf(v4.y + BN_EPS);
    const float s2 = g4.z * rsqrtf(v4.z + BN_EPS);
    const float s3 = g4.w * rsqrtf(v4.w + BN_EPS);
    const float h0 = b4.x - m4.x * s0 + ba4.x * s0;
    const float h1 = b4.y - m4.y * s1 + ba4.y * s1;
    const float h2 = b4.z - m4.z * s2 + ba4.z * s2;
    const float h3 = b4.w - m4.w * s3 + ba4.w * s3;

    const int ntiles = (n + 15) >> 4;
    const int stride = gridDim.x * 4;
    for (int tile = blockIdx.x * 4 + w; tile < ntiles; tile += stride) {
        const int node0 = tile << 4;

        // ---- gather-agg phase: 4 passes of 4 nodes ----
        for (int p = 0; p < 4; ++p) {
            const int r = p * 4 + half;            // local row 0..15
            const int node = node0 + r;
            const bool ok = (node < n);
            const int nodeg = ok ? node : n;       // pad row if OOB
            const int beg = ok ? rp[node] : 0;
            const int end = ok ? rp[node + 1] : 0;

            half4v selfv = *(const half4v*)&yh[((size_t)nodeg << 6) + fo];
            float a0 = (float)selfv[0], a1 = (float)selfv[1];
            float a2 = (float)selfv[2], a3 = (float)selfv[3];

            for (int i = beg; i < end; i += 8) {
                int c[8];
                half4v v[8];
                #pragma unroll
                for (int j = 0; j < 8; ++j) c[j] = (i + j < end) ? col[i + j] : n;
                #pragma unroll
                for (int j = 0; j < 8; ++j)
                    v[j] = *(const half4v*)&yh[((size_t)c[j] << 6) + fo];
                #pragma unroll
                for (int j = 0; j < 8; ++j) {
                    a0 += (float)v[j][0];
                    a1 += (float)v[j][1];
                    a2 += (float)v[j][2];
                    a3 += (float)v[j][3];
                }
            }
            half4v o;
            o[0] = (_Float16)fmaxf(fmaf(a0, s0, h0), 0.f);
            o[1] = (_Float16)fmaxf(fmaf(a1, s1, h1), 0.f);
            o[2] = (_Float16)fmaxf(fmaf(a2, s2, h2), 0.f);
            o[3] = (_Float16)fmaxf(fmaf(a3, s3, h3), 0.f);
            *(half4v*)&tt[w][r][fo] = o;
        }
        asm volatile("s_waitcnt lgkmcnt(0)" ::: "memory");
        __builtin_amdgcn_sched_barrier(0);

        // ---- MFMA phase ----
        half8v at[2];
        #pragma unroll
        for (int kk = 0; kk < 2; ++kk)
            at[kk] = *(const half8v*)&tt[w][sub][kk * 32 + half * 8];

        float4v accz[4];
        #pragma unroll
        for (int nt = 0; nt < 4; ++nt) {
            float4v c = {0.f, 0.f, 0.f, 0.f};
            c = __builtin_amdgcn_mfma_f32_16x16x32_f16(at[0], wbf[0][nt], c, 0, 0, 0);
            c = __builtin_amdgcn_mfma_f32_16x16x32_f16(at[1], wbf[1][nt], c, 0, 0, 0);
            accz[nt] = c;
        }

        if (LAST) {
            #pragma unroll
            for (int nt = 0; nt < 4; ++nt)
                #pragma unroll
                for (int r = 0; r < 4; ++r) {
                    int m = node0 + half * 4 + r;
                    if (m < n)
                        outh[((size_t)m << 6) + nt * 16 + sub] =
                            (_Float16)fmaxf(accz[nt][r] + bbr[nt], 0.f);
                }
        } else {
            #pragma unroll
            for (int nt = 0; nt < 4; ++nt)
                #pragma unroll
                for (int r = 0; r < 4; ++r)
                    zt[w][half * 4 + r][nt * 16 + sub] =
                        (_Float16)fmaxf(accz[nt][r] + bbr[nt], 0.f);
            asm volatile("s_waitcnt lgkmcnt(0)" ::: "memory");
            __builtin_amdgcn_sched_barrier(0);
            half8v az[2];
            #pragma unroll
            for (int kk = 0; kk < 2; ++kk)
                az[kk] = *(const half8v*)&zt[w][sub][kk * 32 + half * 8];

            #pragma unroll
            for (int nt = 0; nt < 4; ++nt) {
                float4v c = {0.f, 0.f, 0.f, 0.f};
                c = __builtin_amdgcn_mfma_f32_16x16x32_f16(az[0], wnf[0][nt], c, 0, 0, 0);
                c = __builtin_amdgcn_mfma_f32_16x16x32_f16(az[1], wnf[1][nt], c, 0, 0, 0);
                #pragma unroll
                for (int r = 0; r < 4; ++r) {
                    int m = node0 + half * 4 + r;
                    if (m < n)
                        outh[((size_t)m << 6) + nt * 16 + sub] = (_Float16)c[r];
                }
            }
        }
    }
}

// ------- fused pool+head: wave = graph (4 graphs/block), 8-deep pooling ----
__global__ __launch_bounds__(256)
void pool_head_kernel(const _Float16* __restrict__ h, const int* __restrict__ gptr,
                      const float* __restrict__ lw1, const float* __restrict__ lb1,
                      const float* __restrict__ lw2, const float* __restrict__ lb2,
                      float* __restrict__ out, int G) {
    __shared__ float s_row[4][64];
    const int w = threadIdx.x >> 6;
    const int d = threadIdx.x & 63;
    const int g = blockIdx.x * 4 + w;
    if (g >= G) return;
    const int beg = gptr[g], end = gptr[g + 1];

    float acc = 0.f;
    int i = beg;
    const int end8 = beg + ((end - beg) & ~7);
    for (; i < end8; i += 8) {
        float v[8];
        #pragma unroll
        for (int j = 0; j < 8; ++j)
            v[j] = (float)h[((size_t)(i + j) << 6) + d];
        #pragma unroll
        for (int j = 0; j < 8; ++j) acc += v[j];
    }
    for (; i < end; ++i) acc += (float)h[((size_t)i << 6) + d];

    s_row[w][d] = acc;
    asm volatile("s_waitcnt lgkmcnt(0)" ::: "memory");
    __builtin_amdgcn_sched_barrier(0);

    float z = lb1[d];
    #pragma unroll 8
    for (int k = 0; k < 64; ++k)
        z = fmaf(s_row[w][k], lw1[k * 64 + d], z);
    z = fmaxf(z, 0.f);
    float r = z * lw2[d];
    #pragma unroll
    for (int off = 32; off > 0; off >>= 1)
        r += __shfl_down(r, off, 64);
    if (d == 0) out[g] = r + lb2[0];
}

extern "C" void kernel_launch(void* const* d_in, const int* in_sizes, int n_in,
                              void* d_out, int out_size, void* d_ws, size_t ws_size,
                              hipStream_t stream) {
    const float* x    = (const float*)d_in[0];
    const int* ei     = (const int*)d_in[1];
    const int* batch  = (const int*)d_in[2];
    const int N = in_sizes[0] / 11;
    const int E = in_sizes[1] / 2;
    const int G = out_size;
    const int* src = ei;
    const int* dst = ei + E;

    const float* p[28];
    for (int i = 0; i < 28; ++i) p[i] = (const float*)d_in[3 + i];
    // p[0..7]=L1 {wa,ba,g,be,m,v,wb,bb}, p[8..15]=L2, p[16..23]=L3
    // p[24]=lw1 p[25]=lb1 p[26]=lw2 p[27]=lb2

    _Float16* yA  = (_Float16*)d_ws;                     // [(N+1),64] fp16
    _Float16* yB  = yA + ((size_t)N + 1) * 64;           // [(N+1),64] fp16
    _Float16* fw  = yB + ((size_t)N + 1) * 64;           // [5*4096] weight frags
    int*   ghist  = (int*)(fw + 5 * 4096);               // [NBUCK*NBLK]
    int*   bsum   = ghist + NBUCK * NBLK;                // [512] raw chunk totals
    int*   rp     = bsum + 512;                          // [N+1]
    int*   gptr   = rp + N + 1;                          // [G+1]
    int*   col    = gptr + G + 1;                        // [E]
    unsigned* pairs = (unsigned*)(col + E);              // [E] packed

    const int chunk     = (E + NBLK - 1) / NBLK;
    const int nscan     = NBUCK * NBLK;
    const int nbScanB   = nscan / 256;                   // 512
    const int nbuckUsed = (N + 255) >> 8;                // 391
    const int nGptrBlocks = (N + 255) / 256;             // 391
    const int ntiles    = (N + 15) >> 4;                 // 6250
    const int nbLayer   = (ntiles + 3) / 4;              // 1563: 1 tile/wave

    _Float16* fwb1 = fw;                 // L1 wb
    _Float16* fwn1 = fw + 4096;          // L2 wa
    _Float16* fwb2 = fw + 2 * 4096;      // L2 wb
    _Float16* fwn2 = fw + 3 * 4096;      // L3 wa
    _Float16* fwb3 = fw + 4 * 4096;      // L3 wb

    // ---- setup: hist || wfrag || gptr (one dispatch) ----
    setup_kernel<<<NBLK + 5 + nGptrBlocks, 256, 0, stream>>>(
        dst, ghist, E, chunk,
        yA + (size_t)N * 64, yB + (size_t)N * 64,
        batch, gptr, N, G,
        p[6], p[8], p[14], p[16], p[22], fw);

    // ---- CSR build (no top-scan dispatch; pre hidden under bin_fill) ----
    scan_block_g<<<nbScanB, 256, 0, stream>>>(ghist, bsum, nscan);
    fill_pre_kernel<<<2048, 256, 0, stream>>>(src, dst, ghist, bsum,
        pairs, E, chunk, x, p[0], yA, N);
    csr_sort_kernel<<<nbuckUsed, 256, 0, stream>>>(pairs, bsum, col, rp, N, E, nbuckUsed);

    // ---- fused layers (ping-pong yA <-> yB) ----
    layer_kernel<false><<<nbLayer, 256, 0, stream>>>(yA, rp, col,
        p[1], p[2], p[3], p[4], p[5], fwb1, p[7], fwn1, yB, N);
    layer_kernel<false><<<nbLayer, 256, 0, stream>>>(yB, rp, col,
        p[9], p[10], p[11], p[12], p[13], fwb2, p[15], fwn2, yA, N);
    layer_kernel<true><<<nbLayer, 256, 0, stream>>>(yA, rp, col,
        p[17], p[18], p[19], p[20], p[21], fwb3, p[23], nullptr, yB, N);

    // ---- fused pool + head ----
    pool_head_kernel<<<(G + 3) / 4, 256, 0, stream>>>(yB, gptr,
        p[24], p[25], p[26], p[27], (float*)d_out, G);
}